// Round 1
// baseline (146.242 us; speedup 1.0000x reference)
//
#include <hip/hip_runtime.h>

#define D_MODEL 4096
#define N_HEADS 32
#define HEAD_DIM 128
#define MAX_SEQ 512

// ---------------------------------------------------------------------------
// Fused Q/K/V projection GEMV: wave (64 lanes) per output row.
// rows 0..4095 -> q = Wq @ query + bq
// rows 4096..8191 -> k_new = Wk @ kv_src + bk
// rows 8192..12287 -> v_new = Wv @ kv_src + bv
// ---------------------------------------------------------------------------
__global__ void qkv_gemv(const float* __restrict__ Wq, const float* __restrict__ bq,
                         const float* __restrict__ Wk, const float* __restrict__ bk,
                         const float* __restrict__ Wv, const float* __restrict__ bv,
                         const float* __restrict__ query, const float* __restrict__ kvsrc,
                         float* __restrict__ qkv_out) {
    const int wid  = (blockIdx.x * blockDim.x + threadIdx.x) >> 6;   // global wave id, [0,12288)
    const int lane = threadIdx.x & 63;
    const int which = wid >> 12;          // 0=q, 1=k, 2=v
    const int row   = wid & (D_MODEL - 1);

    const float* W = (which == 0) ? Wq : (which == 1) ? Wk : Wv;
    const float* b = (which == 0) ? bq : (which == 1) ? bk : bv;
    const float* x = (which == 0) ? query : kvsrc;

    const float4* W4 = (const float4*)(W + (size_t)row * D_MODEL);
    const float4* x4 = (const float4*)x;

    float acc = 0.f;
#pragma unroll
    for (int j = 0; j < D_MODEL / 4; j += 64) {
        float4 w = W4[j + lane];
        float4 v = x4[j + lane];
        acc += w.x * v.x + w.y * v.y + w.z * v.z + w.w * v.w;
    }
#pragma unroll
    for (int off = 32; off > 0; off >>= 1) acc += __shfl_xor(acc, off);
    if (lane == 0) qkv_out[wid] = acc + b[row];
}

// ---------------------------------------------------------------------------
// Copy KV caches to output with the row at position `step` replaced.
// float4 granularity: i = h*16384 + s*32 + d4
// ---------------------------------------------------------------------------
__global__ void kv_update(const float4* __restrict__ kb, const float4* __restrict__ vb,
                          const float4* __restrict__ knew, const float4* __restrict__ vnew,
                          const int* __restrict__ step_p,
                          float4* __restrict__ out_kb, float4* __restrict__ out_vb) {
    const int step = *step_p;
    const int n4 = N_HEADS * MAX_SEQ * HEAD_DIM / 4;   // 524288
    for (int i = blockIdx.x * blockDim.x + threadIdx.x; i < n4; i += gridDim.x * blockDim.x) {
        const int s  = (i >> 5) & (MAX_SEQ - 1);
        const int h  = i >> 14;
        const int d4 = i & 31;
        if (s == step) {
            out_kb[i] = knew[h * 32 + d4];
            out_vb[i] = vnew[h * 32 + d4];
        } else {
            out_kb[i] = kb[i];
            out_vb[i] = vb[i];
        }
    }
}

// ---------------------------------------------------------------------------
// Attention for one head per block (256 threads = 4 waves).
// Reads the UPDATED caches (out_kb/out_vb), q from workspace.
// ---------------------------------------------------------------------------
__global__ void attn_kernel(const float* __restrict__ q,
                            const float* __restrict__ kb,
                            const float* __restrict__ vb,
                            const int* __restrict__ step_p,
                            float* __restrict__ attn_out) {
    const int h   = blockIdx.x;
    const int tid = threadIdx.x;
    const int n   = *step_p + 1;                  // positions [0, n)

    __shared__ float sq[HEAD_DIM];
    __shared__ float w[MAX_SEQ];
    __shared__ float red_m[4];
    __shared__ float red_s[4];
    __shared__ float po[2][HEAD_DIM];

    if (tid < HEAD_DIM) sq[tid] = q[h * HEAD_DIM + tid];
    __syncthreads();

    const float scale = 0.08838834764831845f;     // 1/sqrt(128)

    // scores
    for (int s = tid; s < n; s += 256) {
        const float4* krow = (const float4*)(kb + ((size_t)(h * MAX_SEQ + s)) * HEAD_DIM);
        const float4* q4   = (const float4*)sq;
        float acc = 0.f;
#pragma unroll
        for (int j = 0; j < HEAD_DIM / 4; ++j) {
            float4 kk = krow[j];
            float4 qq = q4[j];
            acc += kk.x * qq.x + kk.y * qq.y + kk.z * qq.z + kk.w * qq.w;
        }
        w[s] = acc * scale;
    }
    __syncthreads();

    // block max
    float m = -1e30f;
    for (int s = tid; s < n; s += 256) m = fmaxf(m, w[s]);
#pragma unroll
    for (int off = 32; off > 0; off >>= 1) m = fmaxf(m, __shfl_xor(m, off));
    if ((tid & 63) == 0) red_m[tid >> 6] = m;
    __syncthreads();
    m = fmaxf(fmaxf(red_m[0], red_m[1]), fmaxf(red_m[2], red_m[3]));
    __syncthreads();

    // exp + block sum
    float part = 0.f;
    for (int s = tid; s < n; s += 256) {
        float e = __expf(w[s] - m);
        w[s] = e;
        part += e;
    }
#pragma unroll
    for (int off = 32; off > 0; off >>= 1) part += __shfl_xor(part, off);
    if ((tid & 63) == 0) red_s[tid >> 6] = part;
    __syncthreads();
    const float l = red_s[0] + red_s[1] + red_s[2] + red_s[3];
    __syncthreads();

    // P @ V : threads split d (128) x s-parity (2)
    const int d  = tid & (HEAD_DIM - 1);
    const int s0 = tid >> 7;
    float acc = 0.f;
    for (int s = s0; s < n; s += 2)
        acc += w[s] * vb[((size_t)(h * MAX_SEQ + s)) * HEAD_DIM + d];
    po[s0][d] = acc;
    __syncthreads();
    if (tid < HEAD_DIM)
        attn_out[h * HEAD_DIM + tid] = (po[0][tid] + po[1][tid]) / l;
}

// ---------------------------------------------------------------------------
// Output projection GEMV: wave per row, out = Wo @ attn + bo
// ---------------------------------------------------------------------------
__global__ void out_gemv(const float* __restrict__ Wo, const float* __restrict__ bo,
                         const float* __restrict__ x, float* __restrict__ out) {
    const int row  = (blockIdx.x * blockDim.x + threadIdx.x) >> 6;
    const int lane = threadIdx.x & 63;

    const float4* W4 = (const float4*)(Wo + (size_t)row * D_MODEL);
    const float4* x4 = (const float4*)x;

    float acc = 0.f;
#pragma unroll
    for (int j = 0; j < D_MODEL / 4; j += 64) {
        float4 w = W4[j + lane];
        float4 v = x4[j + lane];
        acc += w.x * v.x + w.y * v.y + w.z * v.z + w.w * v.w;
    }
#pragma unroll
    for (int off = 32; off > 0; off >>= 1) acc += __shfl_xor(acc, off);
    if (lane == 0) out[row] = acc + bo[row];
}

extern "C" void kernel_launch(void* const* d_in, const int* in_sizes, int n_in,
                              void* d_out, int out_size, void* d_ws, size_t ws_size,
                              hipStream_t stream) {
    const float* query  = (const float*)d_in[0];
    const float* kvsrc  = (const float*)d_in[1];
    const int*   step_p = (const int*)d_in[2];
    const float* kb     = (const float*)d_in[3];
    const float* vb     = (const float*)d_in[4];
    const float* Wq     = (const float*)d_in[5];
    const float* bq     = (const float*)d_in[6];
    const float* Wk     = (const float*)d_in[7];
    const float* bk     = (const float*)d_in[8];
    const float* Wv     = (const float*)d_in[9];
    const float* bv     = (const float*)d_in[10];
    const float* Wo     = (const float*)d_in[11];
    const float* bo     = (const float*)d_in[12];

    float* out    = (float*)d_out;                                   // [4096]
    float* out_kb = out + D_MODEL;                                   // [32*512*128]
    float* out_vb = out_kb + N_HEADS * MAX_SEQ * HEAD_DIM;           // [32*512*128]

    float* qkv  = (float*)d_ws;            // q[4096], k_new[4096], v_new[4096]
    float* qv   = qkv;
    float* knew = qkv + D_MODEL;
    float* vnew = qkv + 2 * D_MODEL;
    float* attn = qkv + 3 * D_MODEL;       // [4096]

    // 1) fused qkv projection: 12288 rows, 1 wave each, 4 waves/block
    qkv_gemv<<<3 * D_MODEL / 4, 256, 0, stream>>>(Wq, bq, Wk, bk, Wv, bv, query, kvsrc, qkv);

    // 2) KV cache copy + scatter at step
    kv_update<<<2048, 256, 0, stream>>>((const float4*)kb, (const float4*)vb,
                                        (const float4*)knew, (const float4*)vnew,
                                        step_p, (float4*)out_kb, (float4*)out_vb);

    // 3) attention per head (reads updated caches)
    attn_kernel<<<N_HEADS, 256, 0, stream>>>(qv, out_kb, out_vb, step_p, attn);

    // 4) output projection
    out_gemv<<<D_MODEL / 4, 256, 0, stream>>>(Wo, bo, attn, out);
}

// Round 2
// 71.692 us; speedup vs baseline: 2.0399x; 2.0399x over previous
//
#include <hip/hip_runtime.h>

#define D_MODEL 4096
#define N_HEADS 32
#define HEAD_DIM 128
#define MAX_SEQ 512
#define SPLITS 8
#define SPLIT_LEN (MAX_SEQ / SPLITS)   // 64

// ---------------------------------------------------------------------------
// Fused Q/K/V projection GEMV: wave (64 lanes) per output row.
// rows 0..4095 -> q ; 4096..8191 -> k_new ; 8192..12287 -> v_new
// ---------------------------------------------------------------------------
__global__ void qkv_gemv(const float* __restrict__ Wq, const float* __restrict__ bq,
                         const float* __restrict__ Wk, const float* __restrict__ bk,
                         const float* __restrict__ Wv, const float* __restrict__ bv,
                         const float* __restrict__ query, const float* __restrict__ kvsrc,
                         float* __restrict__ qkv_out) {
    const int wid  = (blockIdx.x * blockDim.x + threadIdx.x) >> 6;   // [0,12288)
    const int lane = threadIdx.x & 63;
    const int which = wid >> 12;          // 0=q, 1=k, 2=v
    const int row   = wid & (D_MODEL - 1);

    const float* W = (which == 0) ? Wq : (which == 1) ? Wk : Wv;
    const float* b = (which == 0) ? bq : (which == 1) ? bk : bv;
    const float* x = (which == 0) ? query : kvsrc;

    const float4* W4 = (const float4*)(W + (size_t)row * D_MODEL);
    const float4* x4 = (const float4*)x;

    float acc = 0.f;
#pragma unroll
    for (int j = 0; j < D_MODEL / 4; j += 64) {
        float4 w = W4[j + lane];
        float4 v = x4[j + lane];
        acc += w.x * v.x + w.y * v.y + w.z * v.z + w.w * v.w;
    }
#pragma unroll
    for (int off = 32; off > 0; off >>= 1) acc += __shfl_xor(acc, off);
    if (lane == 0) qkv_out[wid] = acc + b[row];
}

// ---------------------------------------------------------------------------
// Copy KV caches to output with the row at position `step` replaced.
// ---------------------------------------------------------------------------
__global__ void kv_update(const float4* __restrict__ kb, const float4* __restrict__ vb,
                          const float4* __restrict__ knew, const float4* __restrict__ vnew,
                          const int* __restrict__ step_p,
                          float4* __restrict__ out_kb, float4* __restrict__ out_vb) {
    const int step = *step_p;
    const int n4 = N_HEADS * MAX_SEQ * HEAD_DIM / 4;   // 524288
    for (int i = blockIdx.x * blockDim.x + threadIdx.x; i < n4; i += gridDim.x * blockDim.x) {
        const int s  = (i >> 5) & (MAX_SEQ - 1);
        const int h  = i >> 14;
        const int d4 = i & 31;
        if (s == step) {
            out_kb[i] = knew[h * 32 + d4];
            out_vb[i] = vnew[h * 32 + d4];
        } else {
            out_kb[i] = kb[i];
            out_vb[i] = vb[i];
        }
    }
}

// ---------------------------------------------------------------------------
// Flash-decode split: block = (head, split of 64 positions).
// Emits partial max pm, partial sum pl, unnormalized partial output po[128].
// ---------------------------------------------------------------------------
__global__ void attn_split(const float* __restrict__ q,
                           const float* __restrict__ kb,
                           const float* __restrict__ vb,
                           const int* __restrict__ step_p,
                           float* __restrict__ pm, float* __restrict__ pl,
                           float* __restrict__ po) {
    const int bid = blockIdx.x;
    const int h   = bid >> 3;
    const int sp  = bid & (SPLITS - 1);
    const int tid = threadIdx.x;
    const int n   = *step_p + 1;
    const int s0  = sp * SPLIT_LEN;
    const int cnt = min(SPLIT_LEN, n - s0);

    if (cnt <= 0) {                               // uniform per block
        if (tid == 0) { pm[bid] = -1e30f; pl[bid] = 0.f; }
        if (tid < HEAD_DIM) po[bid * HEAD_DIM + tid] = 0.f;
        return;
    }

    __shared__ float sq[HEAD_DIM];
    __shared__ float w[SPLIT_LEN];
    __shared__ float pv[2][HEAD_DIM];

    if (tid < HEAD_DIM) sq[tid] = q[h * HEAD_DIM + tid];
    __syncthreads();

    // scores: 4 threads per position, 32 elems each, shuffle-reduce group of 4
    {
        const int p = tid >> 2;
        const int g = tid & 3;
        float acc = 0.f;
        if (p < cnt) {
            const float4* krow = (const float4*)(kb + ((size_t)(h * MAX_SEQ + s0 + p)) * HEAD_DIM);
            const float4* q4   = (const float4*)sq;
#pragma unroll
            for (int j = 0; j < 8; ++j) {
                float4 kk = krow[g * 8 + j];
                float4 qq = q4[g * 8 + j];
                acc += kk.x * qq.x + kk.y * qq.y + kk.z * qq.z + kk.w * qq.w;
            }
        }
        acc += __shfl_xor(acc, 1);
        acc += __shfl_xor(acc, 2);
        if ((g == 0) && (p < cnt)) w[p] = acc * 0.08838834764831845f;
    }
    __syncthreads();

    // partial softmax over w[0..cnt): one wave (cnt <= 64)
    if (tid < 64) {
        float mv = (tid < cnt) ? w[tid] : -1e30f;
#pragma unroll
        for (int off = 32; off > 0; off >>= 1) mv = fmaxf(mv, __shfl_xor(mv, off));
        float e = (tid < cnt) ? __expf(w[tid] - mv) : 0.f;
        if (tid < cnt) w[tid] = e;
        float sum = e;
#pragma unroll
        for (int off = 32; off > 0; off >>= 1) sum += __shfl_xor(sum, off);
        if (tid == 0) { pm[bid] = mv; pl[bid] = sum; }
    }
    __syncthreads();

    // P @ V : thread = (s-parity, d); coalesced across d
    const int d    = tid & (HEAD_DIM - 1);
    const int half = tid >> 7;
    float acc = 0.f;
    for (int s = half; s < cnt; s += 2)
        acc += w[s] * vb[((size_t)(h * MAX_SEQ + s0 + s)) * HEAD_DIM + d];
    pv[half][d] = acc;
    __syncthreads();
    if (tid < HEAD_DIM)
        po[bid * HEAD_DIM + tid] = pv[0][tid] + pv[1][tid];
}

// ---------------------------------------------------------------------------
// Combine the 8 partials per head.
// ---------------------------------------------------------------------------
__global__ void attn_combine(const float* __restrict__ pm, const float* __restrict__ pl,
                             const float* __restrict__ po, float* __restrict__ attn_out) {
    const int h = blockIdx.x;
    const int d = threadIdx.x;                    // 128 threads
    float m = -1e30f;
#pragma unroll
    for (int j = 0; j < SPLITS; ++j) m = fmaxf(m, pm[h * SPLITS + j]);
    float l = 0.f, o = 0.f;
#pragma unroll
    for (int j = 0; j < SPLITS; ++j) {
        float sc = __expf(pm[h * SPLITS + j] - m);   // 0 for empty splits
        l += pl[h * SPLITS + j] * sc;
        o += po[(h * SPLITS + j) * HEAD_DIM + d] * sc;
    }
    attn_out[h * HEAD_DIM + d] = o / l;
}

// ---------------------------------------------------------------------------
// Output projection GEMV: wave per row.
// ---------------------------------------------------------------------------
__global__ void out_gemv(const float* __restrict__ Wo, const float* __restrict__ bo,
                         const float* __restrict__ x, float* __restrict__ out) {
    const int row  = (blockIdx.x * blockDim.x + threadIdx.x) >> 6;
    const int lane = threadIdx.x & 63;

    const float4* W4 = (const float4*)(Wo + (size_t)row * D_MODEL);
    const float4* x4 = (const float4*)x;

    float acc = 0.f;
#pragma unroll
    for (int j = 0; j < D_MODEL / 4; j += 64) {
        float4 w = W4[j + lane];
        float4 v = x4[j + lane];
        acc += w.x * v.x + w.y * v.y + w.z * v.z + w.w * v.w;
    }
#pragma unroll
    for (int off = 32; off > 0; off >>= 1) acc += __shfl_xor(acc, off);
    if (lane == 0) out[row] = acc + bo[row];
}

extern "C" void kernel_launch(void* const* d_in, const int* in_sizes, int n_in,
                              void* d_out, int out_size, void* d_ws, size_t ws_size,
                              hipStream_t stream) {
    const float* query  = (const float*)d_in[0];
    const float* kvsrc  = (const float*)d_in[1];
    const int*   step_p = (const int*)d_in[2];
    const float* kb     = (const float*)d_in[3];
    const float* vb     = (const float*)d_in[4];
    const float* Wq     = (const float*)d_in[5];
    const float* bq     = (const float*)d_in[6];
    const float* Wk     = (const float*)d_in[7];
    const float* bk     = (const float*)d_in[8];
    const float* Wv     = (const float*)d_in[9];
    const float* bv     = (const float*)d_in[10];
    const float* Wo     = (const float*)d_in[11];
    const float* bo     = (const float*)d_in[12];

    float* out    = (float*)d_out;                                   // [4096]
    float* out_kb = out + D_MODEL;                                   // [32*512*128]
    float* out_vb = out_kb + N_HEADS * MAX_SEQ * HEAD_DIM;           // [32*512*128]

    float* qkv  = (float*)d_ws;            // q[4096], k_new[4096], v_new[4096]
    float* qv   = qkv;
    float* knew = qkv + D_MODEL;
    float* vnew = qkv + 2 * D_MODEL;
    float* attn = qkv + 3 * D_MODEL;       // [4096]
    float* pm   = attn + D_MODEL;          // [256]
    float* pl   = pm + N_HEADS * SPLITS;   // [256]
    float* po   = pl + N_HEADS * SPLITS;   // [256*128]

    // 1) fused qkv projection: 12288 rows, 1 wave each
    qkv_gemv<<<3 * D_MODEL / 4, 256, 0, stream>>>(Wq, bq, Wk, bk, Wv, bv, query, kvsrc, qkv);

    // 2) KV cache copy + scatter at step
    kv_update<<<2048, 256, 0, stream>>>((const float4*)kb, (const float4*)vb,
                                        (const float4*)knew, (const float4*)vnew,
                                        step_p, (float4*)out_kb, (float4*)out_vb);

    // 3) flash-decode attention: 32 heads x 8 splits
    attn_split<<<N_HEADS * SPLITS, 256, 0, stream>>>(qv, out_kb, out_vb, step_p, pm, pl, po);
    attn_combine<<<N_HEADS, HEAD_DIM, 0, stream>>>(pm, pl, po, attn);

    // 4) output projection
    out_gemv<<<D_MODEL / 4, 256, 0, stream>>>(Wo, bo, attn, out);
}

// Round 3
// 69.959 us; speedup vs baseline: 2.0904x; 1.0248x over previous
//
#include <hip/hip_runtime.h>

#define D_MODEL 4096
#define N_HEADS 32
#define HEAD_DIM 128
#define MAX_SEQ 512
#define SPLITS 8
#define SPLIT_LEN (MAX_SEQ / SPLITS)   // 64

// ---------------------------------------------------------------------------
// Fused Q/K/V projection GEMV.
// 2 rows per wave, 2-deep load prefetch (6 loads in flight/wave).
// 6144 waves = 1536 blocks = 6 blocks/CU -> all-resident, no tail.
// For K/V rows, lane 0 also scatters the value into the step-row of the
// output KV cache (replaces the knew/vnew indirection).
// ---------------------------------------------------------------------------
__global__ __launch_bounds__(256) void qkv_gemv(
        const float* __restrict__ Wq, const float* __restrict__ bq,
        const float* __restrict__ Wk, const float* __restrict__ bk,
        const float* __restrict__ Wv, const float* __restrict__ bv,
        const float* __restrict__ query, const float* __restrict__ kvsrc,
        const int* __restrict__ step_p,
        float* __restrict__ qkv_out,
        float* __restrict__ out_kb, float* __restrict__ out_vb) {
    const int wid  = (blockIdx.x * blockDim.x + threadIdx.x) >> 6;   // [0,6144)
    const int lane = threadIdx.x & 63;
    const int r0   = wid << 1;            // even row in [0,12288), pair never straddles a matrix
    const int which = r0 >> 12;           // 0=q, 1=k, 2=v
    const int row   = r0 & (D_MODEL - 1);

    const float* W = (which == 0) ? Wq : (which == 1) ? Wk : Wv;
    const float* b = (which == 0) ? bq : (which == 1) ? bk : bv;
    const float* x = (which == 0) ? query : kvsrc;

    const float4* A = (const float4*)(W + (size_t)row * D_MODEL);
    const float4* B = A + D_MODEL / 4;
    const float4* X = (const float4*)x;

    float4 a0 = A[lane],      b0 = B[lane],      x0 = X[lane];
    float4 a1 = A[64 + lane], b1 = B[64 + lane], x1 = X[64 + lane];
    float acc0 = 0.f, acc1 = 0.f;
#pragma unroll
    for (int j = 0; j < 16; ++j) {
        float4 ac = a0, bc = b0, xc = x0;
        a0 = a1; b0 = b1; x0 = x1;
        if (j < 14) {
            const int o = (j + 2) * 64 + lane;
            a1 = A[o]; b1 = B[o]; x1 = X[o];
        }
        acc0 += ac.x * xc.x + ac.y * xc.y + ac.z * xc.z + ac.w * xc.w;
        acc1 += bc.x * xc.x + bc.y * xc.y + bc.z * xc.z + bc.w * xc.w;
    }
#pragma unroll
    for (int off = 32; off > 0; off >>= 1) {
        acc0 += __shfl_xor(acc0, off);
        acc1 += __shfl_xor(acc1, off);
    }
    if (lane == 0) {
        const float v0 = acc0 + b[row];
        const float v1 = acc1 + b[row + 1];
        qkv_out[r0]     = v0;
        qkv_out[r0 + 1] = v1;
        if (which != 0) {                     // scatter k_new / v_new at `step`
            const int step = *step_p;
            float* dst = (which == 1) ? out_kb : out_vb;
            const int h0 = row >> 7, d0 = row & (HEAD_DIM - 1);
            dst[((size_t)h0 * MAX_SEQ + step) * HEAD_DIM + d0]     = v0;
            const int r1 = row + 1;
            dst[((size_t)(r1 >> 7) * MAX_SEQ + step) * HEAD_DIM + (r1 & (HEAD_DIM - 1))] = v1;
        }
    }
}

// ---------------------------------------------------------------------------
// Copy KV caches to output, skipping the step-row (qkv_gemv writes it).
// 2 float4 per thread; disjoint addresses vs qkv_gemv's scatter.
// ---------------------------------------------------------------------------
__global__ void kv_update(const float4* __restrict__ kb, const float4* __restrict__ vb,
                          const int* __restrict__ step_p,
                          float4* __restrict__ out_kb, float4* __restrict__ out_vb) {
    const int step = *step_p;
    int i = blockIdx.x * blockDim.x + threadIdx.x;
#pragma unroll
    for (int t = 0; t < 2; ++t, i += 1024 * 256) {
        const int s = (i >> 5) & (MAX_SEQ - 1);
        if (s != step) {
            out_kb[i] = kb[i];
            out_vb[i] = vb[i];
        }
    }
}

// ---------------------------------------------------------------------------
// Flash-decode split: block = (head, split of 64 positions).
// ---------------------------------------------------------------------------
__global__ void attn_split(const float* __restrict__ q,
                           const float* __restrict__ kb,
                           const float* __restrict__ vb,
                           const int* __restrict__ step_p,
                           float* __restrict__ pm, float* __restrict__ pl,
                           float* __restrict__ po) {
    const int bid = blockIdx.x;
    const int h   = bid >> 3;
    const int sp  = bid & (SPLITS - 1);
    const int tid = threadIdx.x;
    const int n   = *step_p + 1;
    const int s0  = sp * SPLIT_LEN;
    const int cnt = min(SPLIT_LEN, n - s0);

    if (cnt <= 0) {
        if (tid == 0) { pm[bid] = -1e30f; pl[bid] = 0.f; }
        if (tid < HEAD_DIM) po[bid * HEAD_DIM + tid] = 0.f;
        return;
    }

    __shared__ float sq[HEAD_DIM];
    __shared__ float w[SPLIT_LEN];
    __shared__ float pv[2][HEAD_DIM];

    if (tid < HEAD_DIM) sq[tid] = q[h * HEAD_DIM + tid];
    __syncthreads();

    // scores: 4 threads per position, 32 elems each
    {
        const int p = tid >> 2;
        const int g = tid & 3;
        float acc = 0.f;
        if (p < cnt) {
            const float4* krow = (const float4*)(kb + ((size_t)(h * MAX_SEQ + s0 + p)) * HEAD_DIM);
            const float4* q4   = (const float4*)sq;
#pragma unroll
            for (int j = 0; j < 8; ++j) {
                float4 kk = krow[g * 8 + j];
                float4 qq = q4[g * 8 + j];
                acc += kk.x * qq.x + kk.y * qq.y + kk.z * qq.z + kk.w * qq.w;
            }
        }
        acc += __shfl_xor(acc, 1);
        acc += __shfl_xor(acc, 2);
        if ((g == 0) && (p < cnt)) w[p] = acc * 0.08838834764831845f;
    }
    __syncthreads();

    // partial softmax (one wave, cnt <= 64)
    if (tid < 64) {
        float mv = (tid < cnt) ? w[tid] : -1e30f;
#pragma unroll
        for (int off = 32; off > 0; off >>= 1) mv = fmaxf(mv, __shfl_xor(mv, off));
        float e = (tid < cnt) ? __expf(w[tid] - mv) : 0.f;
        if (tid < cnt) w[tid] = e;
        float sum = e;
#pragma unroll
        for (int off = 32; off > 0; off >>= 1) sum += __shfl_xor(sum, off);
        if (tid == 0) { pm[bid] = mv; pl[bid] = sum; }
    }
    __syncthreads();

    // P @ V
    const int d    = tid & (HEAD_DIM - 1);
    const int half = tid >> 7;
    float acc = 0.f;
    for (int s = half; s < cnt; s += 2)
        acc += w[s] * vb[((size_t)(h * MAX_SEQ + s0 + s)) * HEAD_DIM + d];
    pv[half][d] = acc;
    __syncthreads();
    if (tid < HEAD_DIM)
        po[bid * HEAD_DIM + tid] = pv[0][tid] + pv[1][tid];
}

__global__ void attn_combine(const float* __restrict__ pm, const float* __restrict__ pl,
                             const float* __restrict__ po, float* __restrict__ attn_out) {
    const int h = blockIdx.x;
    const int d = threadIdx.x;                    // 128 threads
    float m = -1e30f;
#pragma unroll
    for (int j = 0; j < SPLITS; ++j) m = fmaxf(m, pm[h * SPLITS + j]);
    float l = 0.f, o = 0.f;
#pragma unroll
    for (int j = 0; j < SPLITS; ++j) {
        float sc = __expf(pm[h * SPLITS + j] - m);
        l += pl[h * SPLITS + j] * sc;
        o += po[(h * SPLITS + j) * HEAD_DIM + d] * sc;
    }
    attn_out[h * HEAD_DIM + d] = o / l;
}

// ---------------------------------------------------------------------------
// Output projection GEMV: split-K, 2 waves per row, 2048 blocks = 32 waves/CU.
// ---------------------------------------------------------------------------
__global__ __launch_bounds__(256) void out_gemv(const float* __restrict__ Wo,
                                                const float* __restrict__ bo,
                                                const float* __restrict__ x,
                                                float* __restrict__ out) {
    __shared__ float r[4];
    const int wv   = threadIdx.x >> 6;
    const int lane = threadIdx.x & 63;
    const int row  = (blockIdx.x << 1) + (wv >> 1);
    const int half = wv & 1;

    const float4* A = (const float4*)(Wo + (size_t)row * D_MODEL) + (half << 9);
    const float4* X = (const float4*)x + (half << 9);

    float4 a0 = A[lane], x0 = X[lane];
    float4 a1 = A[64 + lane], x1 = X[64 + lane];
    float acc = 0.f;
#pragma unroll
    for (int j = 0; j < 8; ++j) {
        float4 ac = a0, xc = x0;
        a0 = a1; x0 = x1;
        if (j < 6) {
            const int o = (j + 2) * 64 + lane;
            a1 = A[o]; x1 = X[o];
        }
        acc += ac.x * xc.x + ac.y * xc.y + ac.z * xc.z + ac.w * xc.w;
    }
#pragma unroll
    for (int off = 32; off > 0; off >>= 1) acc += __shfl_xor(acc, off);
    if (lane == 0) r[wv] = acc;
    __syncthreads();
    if (threadIdx.x < 2) {
        const int rr = (blockIdx.x << 1) + threadIdx.x;
        out[rr] = r[threadIdx.x * 2] + r[threadIdx.x * 2 + 1] + bo[rr];
    }
}

extern "C" void kernel_launch(void* const* d_in, const int* in_sizes, int n_in,
                              void* d_out, int out_size, void* d_ws, size_t ws_size,
                              hipStream_t stream) {
    const float* query  = (const float*)d_in[0];
    const float* kvsrc  = (const float*)d_in[1];
    const int*   step_p = (const int*)d_in[2];
    const float* kb     = (const float*)d_in[3];
    const float* vb     = (const float*)d_in[4];
    const float* Wq     = (const float*)d_in[5];
    const float* bq     = (const float*)d_in[6];
    const float* Wk     = (const float*)d_in[7];
    const float* bk     = (const float*)d_in[8];
    const float* Wv     = (const float*)d_in[9];
    const float* bv     = (const float*)d_in[10];
    const float* Wo     = (const float*)d_in[11];
    const float* bo     = (const float*)d_in[12];

    float* out    = (float*)d_out;                                   // [4096]
    float* out_kb = out + D_MODEL;                                   // [32*512*128]
    float* out_vb = out_kb + N_HEADS * MAX_SEQ * HEAD_DIM;           // [32*512*128]

    float* qkv  = (float*)d_ws;            // q[4096], k_new[4096], v_new[4096]
    float* qv   = qkv;
    float* attn = qkv + 3 * D_MODEL;       // [4096]
    float* pm   = attn + D_MODEL;          // [256]
    float* pl   = pm + N_HEADS * SPLITS;   // [256]
    float* po   = pl + N_HEADS * SPLITS;   // [256*128]

    // 1) fused qkv projection (+ direct scatter of k_new/v_new at step)
    qkv_gemv<<<1536, 256, 0, stream>>>(Wq, bq, Wk, bk, Wv, bv, query, kvsrc,
                                       step_p, qkv, out_kb, out_vb);

    // 2) KV cache copy (skips step-row)
    kv_update<<<1024, 256, 0, stream>>>((const float4*)kb, (const float4*)vb,
                                        step_p, (float4*)out_kb, (float4*)out_vb);

    // 3) flash-decode attention: 32 heads x 8 splits
    attn_split<<<N_HEADS * SPLITS, 256, 0, stream>>>(qv, out_kb, out_vb, step_p, pm, pl, po);
    attn_combine<<<N_HEADS, HEAD_DIM, 0, stream>>>(pm, pl, po, attn);

    // 4) output projection (split-K)
    out_gemv<<<2048, 256, 0, stream>>>(Wo, bo, attn, out);
}